// Round 1
// baseline (1286.914 us; speedup 1.0000x reference)
//
#include <hip/hip_runtime.h>
#include <stdint.h>

#define D_IN  128
#define D_OUT 64
#define NEG_SLOPE 0.2f

// ---------------------------------------------------------------------------
// Fused skinny GEMM + attention score:
//   msg[row][j]  = sum_k x[row][k] * w[k][j]        (j = 0..63, one wave/row)
//   score[row]   = sum_j msg[row][j] * att[att_off + j]
// w staged in LDS (128x64 fp32 = 32 KB). Lanes j=0..63 read wl[k*64+j]:
// stride-1 across 32 banks -> 2 lanes/bank = conflict-free on CDNA4.
// ---------------------------------------------------------------------------
__global__ void msg_score_kernel(const float* __restrict__ x,
                                 const float* __restrict__ w,
                                 const float* __restrict__ att, int att_off,
                                 float* __restrict__ msg,
                                 float* __restrict__ score,
                                 int n_rows) {
    __shared__ float wl[D_IN * D_OUT];
    const int tid = threadIdx.x;

    // stage w -> LDS, vectorized
    const float4* w4  = (const float4*)w;
    float4*       wl4 = (float4*)wl;
    for (int i = tid; i < (D_IN * D_OUT) / 4; i += blockDim.x) wl4[i] = w4[i];
    __syncthreads();

    const int gtid = blockIdx.x * blockDim.x + tid;
    const int row  = gtid >> 6;   // 64 threads (one wave) per row
    const int j    = tid & 63;
    if (row >= n_rows) return;

    const float4* x4 = (const float4*)(x + (size_t)row * D_IN);
    float acc = 0.f;
#pragma unroll
    for (int k4 = 0; k4 < D_IN / 4; ++k4) {
        float4 xv = x4[k4];   // wave-uniform load (hardware broadcast)
        acc += xv.x * wl[(k4 * 4 + 0) * D_OUT + j];
        acc += xv.y * wl[(k4 * 4 + 1) * D_OUT + j];
        acc += xv.z * wl[(k4 * 4 + 2) * D_OUT + j];
        acc += xv.w * wl[(k4 * 4 + 3) * D_OUT + j];
    }
    msg[(size_t)row * D_OUT + j] = acc;

    // score = wave-reduce(acc * a[j]) over the 64-lane wave
    float v = acc * att[att_off + j];
#pragma unroll
    for (int off = 32; off > 0; off >>= 1) v += __shfl_down(v, off, 64);
    if (j == 0) score[row] = v;
}

// ---------------------------------------------------------------------------
// Per-edge leaky-relu score + f64 segment sums (cancellation-safe: e_row_sum
// can cancel to ~1e-4 while edges are O(1); fp32 accumulation error would be
// ~1% of the amplified e_att -- too close to the 2%-of-absmax threshold).
// ---------------------------------------------------------------------------
__global__ void edge_sum_kernel(const int* __restrict__ row_idx,
                                const int* __restrict__ col_idx,
                                const float* __restrict__ s_score,
                                const float* __restrict__ t_score,
                                double* __restrict__ e_row_sum,
                                double* __restrict__ f_row_sum,
                                int nnz) {
    const int i = blockIdx.x * blockDim.x + threadIdx.x;
    if (i >= nnz) return;
    const int r = row_idx[i];
    const int c = col_idx[i];
    const float xv = s_score[c] + t_score[r];
    const float e  = xv >= 0.f ? xv : NEG_SLOPE * xv;
    atomicAdd(&e_row_sum[r], (double)e);
    atomicAdd(&f_row_sum[c], (double)e);
}

// ---------------------------------------------------------------------------
// Wave-per-edge scatter: lane j owns output component j.
//   mot[r][j] += (edge/e_row_sum[r]) * nbhd * s_msg[c][j]
//   mos[c][j] += (edge/f_row_sum[c]) * nbhd * t_msg[r][j]
// All 64-lane row reads are 256 B coalesced. Edge is recomputed from the
// (L2-resident) score arrays instead of materializing 8 MB of edge values.
// ---------------------------------------------------------------------------
__global__ void scatter_kernel(const int* __restrict__ row_idx,
                               const int* __restrict__ col_idx,
                               const float* __restrict__ s_score,
                               const float* __restrict__ t_score,
                               const double* __restrict__ e_row_sum,
                               const double* __restrict__ f_row_sum,
                               const float* __restrict__ nbhd,
                               const float* __restrict__ s_msg,
                               const float* __restrict__ t_msg,
                               float* __restrict__ mos,
                               float* __restrict__ mot,
                               int nnz) {
    const int wave = (int)((blockIdx.x * (size_t)blockDim.x + threadIdx.x) >> 6);
    const int lane = threadIdx.x & 63;
    if (wave >= nnz) return;

    const int r = row_idx[wave];   // wave-uniform
    const int c = col_idx[wave];

    const float xv = s_score[c] + t_score[r];
    const float e  = xv >= 0.f ? xv : NEG_SLOPE * xv;

    double ers = e_row_sum[r]; if (ers == 0.0) ers = 1.0;
    double frs = f_row_sum[c]; if (frs == 0.0) frs = 1.0;

    const float nb = nbhd[wave];
    const float ev = (float)((double)e / ers) * nb;
    const float fv = (float)((double)e / frs) * nb;

    const float sm = s_msg[(size_t)c * D_OUT + lane];
    const float tm = t_msg[(size_t)r * D_OUT + lane];

    atomicAdd(&mot[(size_t)r * D_OUT + lane], ev * sm);
    atomicAdd(&mos[(size_t)c * D_OUT + lane], fv * tm);
}

// ---------------------------------------------------------------------------
extern "C" void kernel_launch(void* const* d_in, const int* in_sizes, int n_in,
                              void* d_out, int out_size, void* d_ws, size_t ws_size,
                              hipStream_t stream) {
    const float* x_source = (const float*)d_in[0];
    const float* x_target = (const float*)d_in[1];
    const float* nbhd     = (const float*)d_in[2];
    const float* w_s      = (const float*)d_in[3];
    const float* w_t      = (const float*)d_in[4];
    const float* att      = (const float*)d_in[5];
    const int*   row_idx  = (const int*)d_in[6];
    const int*   col_idx  = (const int*)d_in[7];

    const int n_s = in_sizes[0] / D_IN;   // 100000
    const int n_t = in_sizes[1] / D_IN;   // 20000
    const int nnz = in_sizes[2];          // 2000000

    float* out = (float*)d_out;
    float* mos = out;                          // (n_s, 64) -- first in return order
    float* mot = out + (size_t)n_s * D_OUT;    // (n_t, 64)

    // workspace layout
    char* ws = (char*)d_ws;
    float* s_msg   = (float*)ws;  ws += sizeof(float) * (size_t)n_s * D_OUT;   // 25.6 MB
    float* t_msg   = (float*)ws;  ws += sizeof(float) * (size_t)n_t * D_OUT;   //  5.1 MB
    float* s_score = (float*)ws;  ws += sizeof(float) * (size_t)n_s;
    float* t_score = (float*)ws;  ws += sizeof(float) * (size_t)n_t;
    ws = (char*)(((uintptr_t)ws + 15) & ~(uintptr_t)15);
    double* e_row_sum = (double*)ws;  ws += sizeof(double) * (size_t)n_t;      // contiguous with
    double* f_row_sum = (double*)ws;  ws += sizeof(double) * (size_t)n_s;      // f_row_sum

    // zero accumulators (ws/d_out are poisoned 0xAA before every launch)
    hipMemsetAsync(e_row_sum, 0, sizeof(double) * (size_t)(n_t + n_s), stream);
    hipMemsetAsync(d_out, 0, sizeof(float) * (size_t)out_size, stream);

    // 1) s_msg + s_score   (wave per row)
    {
        int total = n_s * 64;
        msg_score_kernel<<<(total + 255) / 256, 256, 0, stream>>>(
            x_source, w_s, att, 0, s_msg, s_score, n_s);
    }
    // 2) t_msg + t_score
    {
        int total = n_t * 64;
        msg_score_kernel<<<(total + 255) / 256, 256, 0, stream>>>(
            x_target, w_t, att, D_OUT, t_msg, t_score, n_t);
    }
    // 3) edge scores -> f64 segment sums
    edge_sum_kernel<<<(nnz + 255) / 256, 256, 0, stream>>>(
        row_idx, col_idx, s_score, t_score, e_row_sum, f_row_sum, nnz);

    // 4) normalized scatter of both messages (wave per edge, 4 edges/block)
    {
        size_t total = (size_t)nnz * 64;
        scatter_kernel<<<(unsigned)((total + 255) / 256), 256, 0, stream>>>(
            row_idx, col_idx, s_score, t_score, e_row_sum, f_row_sum,
            nbhd, s_msg, t_msg, mos, mot, nnz);
    }
}